// Round 5
// baseline (293.406 us; speedup 1.0000x reference)
//
#include <hip/hip_runtime.h>

// Problem constants (B=1)
#define L_SEQ 4096
#define C_DIM 1024
#define H_NUM 16
#define D_HEAD 64
#define LDQKV 3072

typedef __bf16 bf16x8 __attribute__((ext_vector_type(8)));
typedef __bf16 bf16x4 __attribute__((ext_vector_type(4)));
typedef float f32x4 __attribute__((ext_vector_type(4)));
typedef float f32x16 __attribute__((ext_vector_type(16)));
typedef unsigned int u32;
typedef u32 u32x4 __attribute__((ext_vector_type(4)));

#define AS1 __attribute__((address_space(1)))
#define AS3 __attribute__((address_space(3)))

#define SC_LOG2E 0.1803368801111204f  // 0.125 * log2(e)

__device__ inline __bf16 f2bf(float f) {
  unsigned u = __builtin_bit_cast(unsigned, f);
  u = (u + 0x7fffu + ((u >> 16) & 1u)) >> 16;
  unsigned short s = (unsigned short)u;
  return __builtin_bit_cast(__bf16, s);
}

__device__ inline void gload_lds16(const __bf16* g, __bf16* l) {
  __builtin_amdgcn_global_load_lds((const AS1 void*)g, (AS3 void*)l, 16, 0, 0);
}

// ---------------- x fp32 -> bf16 ----------------
__global__ __launch_bounds__(256) void cvt_f32_bf16(const float* __restrict__ in,
                                                    __bf16* __restrict__ out) {
  int i = (blockIdx.x * 256 + threadIdx.x) * 4;
  float4 v = *(const float4*)(in + i);
  bf16x4 o = {f2bf(v.x), f2bf(v.y), f2bf(v.z), f2bf(v.w)};
  *(bf16x4*)(out + i) = o;
}

// ---------------- 4x W (K x N) fp32 -> Wt (N x K) bf16, fused ----------------
__global__ __launch_bounds__(256) void transpose_cvt4(const float* __restrict__ W0,
                                                      const float* __restrict__ W1,
                                                      const float* __restrict__ W2,
                                                      const float* __restrict__ W3,
                                                      __bf16* __restrict__ dst) {
  __shared__ float t[32][33];
  const int z = blockIdx.z;
  const float* W = (z == 0) ? W0 : (z == 1) ? W1 : (z == 2) ? W2 : W3;
  __bf16* Wt = dst + (size_t)z * 1048576;
  const int tx = threadIdx.x, ty = threadIdx.y;
  const int c0 = blockIdx.x * 32, r0 = blockIdx.y * 32;
#pragma unroll
  for (int k = 0; k < 4; ++k)
    t[ty + k * 8][tx] = W[(size_t)(r0 + ty + k * 8) * C_DIM + c0 + tx];
  __syncthreads();
#pragma unroll
  for (int k = 0; k < 4; ++k)
    Wt[(size_t)(c0 + ty + k * 8) * C_DIM + r0 + tx] = f2bf(t[tx][ty + k * 8]);
}

// ---------------- V slice of QKV -> Vt [C][L] bf16 ----------------
__global__ __launch_bounds__(256) void transpose_v(const __bf16* __restrict__ QKV,
                                                   __bf16* __restrict__ Vt) {
  __shared__ __bf16 t[32][34];
  const int tx = threadIdx.x, ty = threadIdx.y;
  const int q0 = blockIdx.x * 32, c0 = blockIdx.y * 32;
#pragma unroll
  for (int k = 0; k < 4; ++k)
    t[ty + k * 8][tx] = QKV[(size_t)(q0 + ty + k * 8) * LDQKV + 2048 + c0 + tx];
  __syncthreads();
#pragma unroll
  for (int k = 0; k < 4; ++k)
    Vt[(size_t)(c0 + ty + k * 8) * L_SEQ + q0 + tx] = t[tx][ty + k * 8];
}

// ---------------- GEMM: C(MxN) = A(MxK,bf16) * Bt(NxK,bf16)^T ----------------
template <bool OUT_BF16>
__global__ __launch_bounds__(256) void gemm_bt(const __bf16* __restrict__ A,
                                               const __bf16* __restrict__ Bt,
                                               void* __restrict__ Cp,
                                               int M, int N, int K,
                                               float cscale, int scale_ncols) {
  __shared__ __bf16 As[128 * 32];
  __shared__ __bf16 Bs[128 * 32];
  const int tid = threadIdx.x;
  const int lane = tid & 63;
  const int wave = tid >> 6;
  const int wm = wave >> 1, wn = wave & 1;
  const int c16 = lane & 15, g4 = lane >> 4;
  const int srow = lane >> 2, scol = (lane & 3) * 8;

  f32x4 acc[4][4] = {};

  const size_t arow0 = (size_t)blockIdx.x * 128;
  const size_t brow0 = (size_t)blockIdx.y * 128;

  for (int kt = 0; kt < K; kt += 32) {
#pragma unroll
    for (int i = 0; i < 2; ++i) {
      const int row = i * 64 + wave * 16 + srow;
      gload_lds16(A + (arow0 + row) * K + kt + scol, As + (i * 64 + wave * 16) * 32);
      gload_lds16(Bt + (brow0 + row) * K + kt + scol, Bs + (i * 64 + wave * 16) * 32);
    }
    __syncthreads();
    bf16x8 af[4], bfr[4];
#pragma unroll
    for (int mi = 0; mi < 4; ++mi)
      af[mi] = *(const bf16x8*)(As + (wm * 64 + mi * 16 + c16) * 32 + g4 * 8);
#pragma unroll
    for (int ni = 0; ni < 4; ++ni)
      bfr[ni] = *(const bf16x8*)(Bs + (wn * 64 + ni * 16 + c16) * 32 + g4 * 8);
#pragma unroll
    for (int mi = 0; mi < 4; ++mi)
#pragma unroll
      for (int ni = 0; ni < 4; ++ni)
        acc[mi][ni] = __builtin_amdgcn_mfma_f32_16x16x32_bf16(af[mi], bfr[ni], acc[mi][ni], 0, 0, 0);
    __syncthreads();
  }

  const float esc = ((int)brow0 < scale_ncols) ? cscale : 1.0f;
#pragma unroll
  for (int mi = 0; mi < 4; ++mi)
#pragma unroll
    for (int ni = 0; ni < 4; ++ni)
#pragma unroll
      for (int i = 0; i < 4; ++i) {
        size_t row = arow0 + wm * 64 + mi * 16 + g4 * 4 + i;
        size_t col = brow0 + wn * 64 + ni * 16 + c16;
        if (OUT_BF16)
          ((__bf16*)Cp)[row * N + col] = f2bf(acc[mi][ni][i] * esc);
        else
          ((float*)Cp)[row * N + col] = acc[mi][ni][i];
      }
}

// ------------- causal flash attention, 32x32 swapped-QK^T, paired ------------
// grid 512 x 128 threads: block p (of 32) handles q-tiles {63-p, p} (64 rows
// each) sequentially => exactly 65 staged KV tiles per block (perfect balance).
// 2 warps x 32 q rows. Lane holds a full P row in regs (T12). 4 blocks/CU.
__global__ __launch_bounds__(128, 2) void attn_fwd(const __bf16* __restrict__ Q,
                                                   const __bf16* __restrict__ Kg,
                                                   const __bf16* __restrict__ Vt,
                                                   __bf16* __restrict__ O) {
  const int bid = blockIdx.x;
  const int h = bid & 15;
  const int p = bid >> 4;      // 0..31
  const int nA = 64 - p;       // seg A = q-tile 63-p: kv tiles 0..63-p
  const int NT = 65;           // nA + (p+1)

  __shared__ __bf16 Ks[2][64 * 64];   // [key][d], XOR-swizzled 16B chunks
  __shared__ __bf16 Vs[2][64 * 64];   // [d][key], XOR-swizzled
  __shared__ __bf16 PoS[2][2048];     // per-warp O-transpose buffer (4KB)

  const int tid = threadIdx.x;
  const int lane = tid & 63;
  const int wave = tid >> 6;          // 0..1
  const int l31 = lane & 31;
  const int hl = lane >> 5;
  const int rl = lane >> 3;
  const int cs = (lane & 7) ^ rl;     // pre-swizzled source chunk
  const int thr = wave * 32 + l31;    // diagonal mask threshold (kr <= thr)

  auto stage = [&](int kv, int b) {
#pragma unroll
    for (int i = 0; i < 4; ++i) {
      const int r = (i * 2 + wave) * 8 + rl;
      gload_lds16(Kg + (size_t)(kv * 64 + r) * LDQKV + h * D_HEAD + cs * 8,
                  &Ks[b][(i * 2 + wave) * 512]);
      gload_lds16(Vt + (size_t)(h * D_HEAD + r) * L_SEQ + kv * 64 + cs * 8,
                  &Vs[b][(i * 2 + wave) * 512]);
    }
  };

  stage(0, 0);

  int qbase = (nA - 1) * 64 + wave * 32;  // segment A q rows
  bf16x8 qf[4];
  {
    const __bf16* qp = Q + (size_t)(qbase + l31) * LDQKV + h * D_HEAD + hl * 8;
#pragma unroll
    for (int s = 0; s < 4; ++s) qf[s] = *(const bf16x8*)(qp + s * 16);
  }

  f32x16 acc0 = {}, acc1 = {};
  float m = -1e30f, lsum = 0.f;
  int cur = 0;

  // per-warp, warp-local epilogue: normalize + transpose via LDS + store
  auto epilogue = [&](int qb) {
    const float rinv = 1.0f / lsum;
    char* const Po = (char*)&PoS[wave][0];
#pragma unroll
    for (int dt = 0; dt < 2; ++dt) {
#pragma unroll
      for (int i = 0; i < 8; ++i) {
        const int r = 2 * i;
        const int d = dt * 32 + (r & 3) + 8 * (r >> 2) + 4 * hl;
        float lo = (dt ? acc1[r] : acc0[r]) * rinv;
        float hi = (dt ? acc1[r + 1] : acc0[r + 1]) * rinv;
        u32 wv;
        asm("v_cvt_pk_bf16_f32 %0, %1, %2" : "=v"(wv) : "v"(lo), "v"(hi));
        *(u32*)(Po + l31 * 128 + (((d >> 3) ^ (l31 & 7)) << 4) + (d & 7) * 2) = wv;
      }
    }
    asm volatile("s_waitcnt lgkmcnt(0)" ::: "memory");
    __builtin_amdgcn_sched_barrier(0);
#pragma unroll
    for (int j = 0; j < 4; ++j) {
      const int qr = lane >> 1;
      const int c = (lane & 1) * 4 + j;
      bf16x8 ov = *(const bf16x8*)(Po + qr * 128 + ((c ^ (qr & 7)) << 4));
      *(bf16x8*)(O + (size_t)(qb + qr) * C_DIM + h * D_HEAD + c * 8) = ov;
    }
  };

  for (int it = 0; it < NT; ++it) {
    if (it + 1 < NT) {
      const int kvn = (it + 1 < nA) ? it + 1 : it + 1 - nA;
      stage(kvn, cur ^ 1);
      asm volatile("s_waitcnt vmcnt(8)" ::: "memory");
    } else {
      asm volatile("s_waitcnt vmcnt(0)" ::: "memory");
    }
    __builtin_amdgcn_sched_barrier(0);
    __builtin_amdgcn_s_barrier();
    __builtin_amdgcn_sched_barrier(0);

    char* const KsB = (char*)&Ks[cur][0];
    char* const VsB = (char*)&Vs[cur][0];
    const bool diag = (it == nA - 1) || (it == NT - 1);

    // S^T = K . Q^T : lane holds q row qbase+l31; key regs kr + {0,32}
    f32x16 st0 = {}, st1 = {};
    __builtin_amdgcn_s_setprio(1);
#pragma unroll
    for (int s = 0; s < 4; ++s) {
      const int ch = s * 2 + hl;
      bf16x8 a0 = *(const bf16x8*)(KsB + l31 * 128 + ((ch ^ (l31 & 7)) << 4));
      bf16x8 a1 = *(const bf16x8*)(KsB + (32 + l31) * 128 + ((ch ^ (l31 & 7)) << 4));
      st0 = __builtin_amdgcn_mfma_f32_32x32x16_bf16(a0, qf[s], st0, 0, 0, 0);
      st1 = __builtin_amdgcn_mfma_f32_32x32x16_bf16(a1, qf[s], st1, 0, 0, 0);
    }
    __builtin_amdgcn_s_setprio(0);

    if (diag) {
#pragma unroll
      for (int r = 0; r < 16; ++r) {
        const int kr = (r & 3) + 8 * (r >> 2) + 4 * hl;
        st0[r] = (kr <= thr) ? st0[r] : -1e30f;
        st1[r] = (kr + 32 <= thr) ? st1[r] : -1e30f;
      }
    }

    // row max: in-lane tree + one cross-half swap
    float t[16];
#pragma unroll
    for (int r = 0; r < 16; ++r) t[r] = fmaxf(st0[r], st1[r]);
#pragma unroll
    for (int w = 8; w > 0; w >>= 1)
#pragma unroll
      for (int r = 0; r < w; ++r) t[r] = fmaxf(t[r], t[r + w]);
    float mx = fmaxf(t[0], __shfl_xor(t[0], 32, 64));
    const float mnew = fmaxf(m, mx);
    const float corr = exp2f(m - mnew);
    m = mnew;

    // exp2 + row sum
#pragma unroll
    for (int r = 0; r < 16; ++r) {
      st0[r] = exp2f(st0[r] - m);
      st1[r] = exp2f(st1[r] - m);
    }
    float sm[16];
#pragma unroll
    for (int r = 0; r < 16; ++r) sm[r] = st0[r] + st1[r];
#pragma unroll
    for (int w = 8; w > 0; w >>= 1)
#pragma unroll
      for (int r = 0; r < w; ++r) sm[r] = sm[r] + sm[r + w];
    float sl = sm[0] + __shfl_xor(sm[0], 32, 64);
    lsum = lsum * corr + sl;
    acc0 *= corr;
    acc1 *= corr;

    // P -> bf16 pk words, cross-half exchange
    u32 w0[8], w1[8];
#pragma unroll
    for (int i = 0; i < 8; ++i) {
      asm("v_cvt_pk_bf16_f32 %0, %1, %2" : "=v"(w0[i]) : "v"(st0[2 * i]), "v"(st0[2 * i + 1]));
      asm("v_cvt_pk_bf16_f32 %0, %1, %2" : "=v"(w1[i]) : "v"(st1[2 * i]), "v"(st1[2 * i + 1]));
    }
    u32 e0a = (u32)__shfl_xor((int)(hl ? w0[0] : w0[2]), 32, 64);
    u32 e0b = (u32)__shfl_xor((int)(hl ? w0[1] : w0[3]), 32, 64);
    u32 e0c = (u32)__shfl_xor((int)(hl ? w0[4] : w0[6]), 32, 64);
    u32 e0d = (u32)__shfl_xor((int)(hl ? w0[5] : w0[7]), 32, 64);
    u32 e1a = (u32)__shfl_xor((int)(hl ? w1[0] : w1[2]), 32, 64);
    u32 e1b = (u32)__shfl_xor((int)(hl ? w1[1] : w1[3]), 32, 64);
    u32 e1c = (u32)__shfl_xor((int)(hl ? w1[4] : w1[6]), 32, 64);
    u32 e1d = (u32)__shfl_xor((int)(hl ? w1[5] : w1[7]), 32, 64);
    u32x4 f0 = hl ? (u32x4){e0a, e0b, w0[2], w0[3]} : (u32x4){w0[0], w0[1], e0a, e0b};
    u32x4 f1 = hl ? (u32x4){e0c, e0d, w0[6], w0[7]} : (u32x4){w0[4], w0[5], e0c, e0d};
    u32x4 f2 = hl ? (u32x4){e1a, e1b, w1[2], w1[3]} : (u32x4){w1[0], w1[1], e1a, e1b};
    u32x4 f3 = hl ? (u32x4){e1c, e1d, w1[6], w1[7]} : (u32x4){w1[4], w1[5], e1c, e1d};
    bf16x8 pb0 = __builtin_bit_cast(bf16x8, f0);
    bf16x8 pb1 = __builtin_bit_cast(bf16x8, f1);
    bf16x8 pb2 = __builtin_bit_cast(bf16x8, f2);
    bf16x8 pb3 = __builtin_bit_cast(bf16x8, f3);

    // O^T += V^T . P^T
    __builtin_amdgcn_s_setprio(1);
#pragma unroll
    for (int s = 0; s < 4; ++s) {
      const bf16x8 pb = (s == 0) ? pb0 : (s == 1) ? pb1 : (s == 2) ? pb2 : pb3;
      const int ch = s * 2 + hl;
      bf16x8 va0 = *(const bf16x8*)(VsB + l31 * 128 + ((ch ^ (l31 & 7)) << 4));
      bf16x8 va1 = *(const bf16x8*)(VsB + (32 + l31) * 128 + ((ch ^ (l31 & 7)) << 4));
      acc0 = __builtin_amdgcn_mfma_f32_32x32x16_bf16(va0, pb, acc0, 0, 0, 0);
      acc1 = __builtin_amdgcn_mfma_f32_32x32x16_bf16(va1, pb, acc1, 0, 0, 0);
    }
    __builtin_amdgcn_s_setprio(0);

    __builtin_amdgcn_sched_barrier(0);
    __builtin_amdgcn_s_barrier();
    __builtin_amdgcn_sched_barrier(0);
    cur ^= 1;

    if (it == nA - 1) {
      // finish segment A; switch to segment B (q-tile p)
      epilogue(qbase);
      qbase = p * 64 + wave * 32;
      const __bf16* qp = Q + (size_t)(qbase + l31) * LDQKV + h * D_HEAD + hl * 8;
#pragma unroll
      for (int s = 0; s < 4; ++s) qf[s] = *(const bf16x8*)(qp + s * 16);
      acc0 = (f32x16){};
      acc1 = (f32x16){};
      m = -1e30f;
      lsum = 0.f;
    }
  }

  epilogue(qbase);
}

extern "C" void kernel_launch(void* const* d_in, const int* in_sizes, int n_in,
                              void* d_out, int out_size, void* d_ws, size_t ws_size,
                              hipStream_t stream) {
  const float* x = (const float*)d_in[0];
  const float* Wq = (const float*)d_in[1];
  const float* Wk = (const float*)d_in[2];
  const float* Wv = (const float*)d_in[3];
  const float* Wo = (const float*)d_in[4];
  float* out = (float*)d_out;

  char* ws = (char*)d_ws;
  __bf16* xb    = (__bf16*)(ws);                 // [0,8M) x bf16; reused as Ab
  __bf16* WqkvT = (__bf16*)(ws + (8u << 20));    // [8M,14M); WoT follows
  __bf16* QKVb  = (__bf16*)(ws + (16u << 20));   // [16M,40M) 4096x3072
  __bf16* Vtb   = (__bf16*)(ws + (40u << 20));   // [40M,48M) 1024x4096
  __bf16* WoT   = WqkvT + (size_t)3 * 1048576;   // [14M,16M)
  __bf16* Ab    = xb;

  cvt_f32_bf16<<<4096, 256, 0, stream>>>(x, xb);

  transpose_cvt4<<<dim3(32, 32, 4), dim3(32, 8), 0, stream>>>(Wq, Wk, Wv, Wo, WqkvT);

  // fused QKV projection; Q columns pre-scaled by 0.125*log2(e)
  gemm_bt<true><<<dim3(L_SEQ / 128, LDQKV / 128), 256, 0, stream>>>(
      xb, WqkvT, QKVb, L_SEQ, LDQKV, C_DIM, SC_LOG2E, 1024);

  transpose_v<<<dim3(L_SEQ / 32, C_DIM / 32), dim3(32, 8), 0, stream>>>(QKVb, Vtb);

  attn_fwd<<<512, 128, 0, stream>>>(QKVb, QKVb + 1024, Vtb, Ab);

  gemm_bt<false><<<dim3(L_SEQ / 128, C_DIM / 128), 256, 0, stream>>>(
      Ab, WoT, out, L_SEQ, C_DIM, C_DIM, 1.0f, 0);
}

// Round 7
// 278.068 us; speedup vs baseline: 1.0552x; 1.0552x over previous
//
#include <hip/hip_runtime.h>

// Problem constants (B=1)
#define L_SEQ 4096
#define C_DIM 1024
#define H_NUM 16
#define D_HEAD 64
#define LDQK 2048

typedef __bf16 bf16x8 __attribute__((ext_vector_type(8)));
typedef __bf16 bf16x4 __attribute__((ext_vector_type(4)));
typedef float f32x4 __attribute__((ext_vector_type(4)));
typedef float f32x16 __attribute__((ext_vector_type(16)));
typedef unsigned int u32;
typedef u32 u32x4 __attribute__((ext_vector_type(4)));

#define AS1 __attribute__((address_space(1)))
#define AS3 __attribute__((address_space(3)))

#define SC_LOG2E 0.1803368801111204f  // 0.125 * log2(e)

__device__ inline __bf16 f2bf(float f) {
  unsigned u = __builtin_bit_cast(unsigned, f);
  u = (u + 0x7fffu + ((u >> 16) & 1u)) >> 16;
  unsigned short s = (unsigned short)u;
  return __builtin_bit_cast(__bf16, s);
}

__device__ inline void gload_lds16(const __bf16* g, __bf16* l) {
  __builtin_amdgcn_global_load_lds((const AS1 void*)g, (AS3 void*)l, 16, 0, 0);
}

// ---------------- x fp32 -> bf16 ----------------
__global__ __launch_bounds__(256) void cvt_f32_bf16(const float* __restrict__ in,
                                                    __bf16* __restrict__ out) {
  int i = (blockIdx.x * 256 + threadIdx.x) * 4;
  float4 v = *(const float4*)(in + i);
  bf16x4 o = {f2bf(v.x), f2bf(v.y), f2bf(v.z), f2bf(v.w)};
  *(bf16x4*)(out + i) = o;
}

// ---------------- 4x W (K x N) fp32 -> Wt (N x K) bf16, fused ----------------
__global__ __launch_bounds__(256) void transpose_cvt4(const float* __restrict__ W0,
                                                      const float* __restrict__ W1,
                                                      const float* __restrict__ W2,
                                                      const float* __restrict__ W3,
                                                      __bf16* __restrict__ dst) {
  __shared__ float t[32][33];
  const int z = blockIdx.z;
  const float* W = (z == 0) ? W0 : (z == 1) ? W1 : (z == 2) ? W2 : W3;
  __bf16* Wt = dst + (size_t)z * 1048576;
  const int tx = threadIdx.x, ty = threadIdx.y;
  const int c0 = blockIdx.x * 32, r0 = blockIdx.y * 32;
#pragma unroll
  for (int k = 0; k < 4; ++k)
    t[ty + k * 8][tx] = W[(size_t)(r0 + ty + k * 8) * C_DIM + c0 + tx];
  __syncthreads();
#pragma unroll
  for (int k = 0; k < 4; ++k)
    Wt[(size_t)(c0 + ty + k * 8) * C_DIM + r0 + tx] = f2bf(t[tx][ty + k * 8]);
}

// ---------------- GEMM: C(MxN) = A(MxK,bf16) * Bt(NxK,bf16)^T ----------------
template <bool OUT_BF16>
__global__ __launch_bounds__(256) void gemm_bt(const __bf16* __restrict__ A,
                                               const __bf16* __restrict__ Bt,
                                               void* __restrict__ Cp,
                                               int M, int N, int K,
                                               float cscale, int scale_ncols) {
  __shared__ __bf16 As[128 * 32];
  __shared__ __bf16 Bs[128 * 32];
  const int tid = threadIdx.x;
  const int lane = tid & 63;
  const int wave = tid >> 6;
  const int wm = wave >> 1, wn = wave & 1;
  const int c16 = lane & 15, g4 = lane >> 4;
  const int srow = lane >> 2, scol = (lane & 3) * 8;

  f32x4 acc[4][4] = {};

  const size_t arow0 = (size_t)blockIdx.x * 128;
  const size_t brow0 = (size_t)blockIdx.y * 128;

  for (int kt = 0; kt < K; kt += 32) {
#pragma unroll
    for (int i = 0; i < 2; ++i) {
      const int row = i * 64 + wave * 16 + srow;
      gload_lds16(A + (arow0 + row) * K + kt + scol, As + (i * 64 + wave * 16) * 32);
      gload_lds16(Bt + (brow0 + row) * K + kt + scol, Bs + (i * 64 + wave * 16) * 32);
    }
    __syncthreads();
    bf16x8 af[4], bfr[4];
#pragma unroll
    for (int mi = 0; mi < 4; ++mi)
      af[mi] = *(const bf16x8*)(As + (wm * 64 + mi * 16 + c16) * 32 + g4 * 8);
#pragma unroll
    for (int ni = 0; ni < 4; ++ni)
      bfr[ni] = *(const bf16x8*)(Bs + (wn * 64 + ni * 16 + c16) * 32 + g4 * 8);
#pragma unroll
    for (int mi = 0; mi < 4; ++mi)
#pragma unroll
      for (int ni = 0; ni < 4; ++ni)
        acc[mi][ni] = __builtin_amdgcn_mfma_f32_16x16x32_bf16(af[mi], bfr[ni], acc[mi][ni], 0, 0, 0);
    __syncthreads();
  }

  const float esc = ((int)brow0 < scale_ncols) ? cscale : 1.0f;
#pragma unroll
  for (int mi = 0; mi < 4; ++mi)
#pragma unroll
    for (int ni = 0; ni < 4; ++ni)
#pragma unroll
      for (int i = 0; i < 4; ++i) {
        size_t row = arow0 + wm * 64 + mi * 16 + g4 * 4 + i;
        size_t col = brow0 + wn * 64 + ni * 16 + c16;
        if (OUT_BF16)
          ((__bf16*)Cp)[row * N + col] = f2bf(acc[mi][ni][i] * esc);
        else
          ((float*)Cp)[row * N + col] = acc[mi][ni][i];
      }
}

// ---------------- causal flash attention, 32x32 swapped-QK^T ------------------
// grid 512 x 256 threads: 32 q-tiles of 128 rows x 16 heads. 4 waves x 32 q.
// bid<256 -> qt=31-g (long, desc); bid>=256 -> qt=g (short, asc): with
// round-robin dispatch, blocks c and c+256 co-reside on one CU and their
// iteration counts sum to exactly 68 -> balanced makespan. bid%8 = h%8 pins
// each head's K/V to one XCD L2. Lane holds a full P row in regs (T12).
__global__ __launch_bounds__(256, 2) void attn_fwd(const __bf16* __restrict__ Q,
                                                   const __bf16* __restrict__ Kg,
                                                   const __bf16* __restrict__ Vt,
                                                   __bf16* __restrict__ O) {
  const int bid = blockIdx.x;
  const int h = bid & 15;
  const int g = (bid >> 4) & 15;
  const int qt = (bid < 256) ? (31 - g) : g;
  const int nt = 2 * qt + 2;

  __shared__ __bf16 Ks[2][64 * 64];  // [key][d], XOR-swizzled 16B chunks
  __shared__ __bf16 Vs[2][64 * 64];  // [d][key], XOR-swizzled

  const int tid = threadIdx.x;
  const int lane = tid & 63;
  const int wave = tid >> 6;
  const int l31 = lane & 31;
  const int hl = lane >> 5;
  const int qbase = qt * 128 + wave * 32;
  const int q = qbase + l31;             // this lane's q row
  const int kvmax_w = (qbase + 31) >> 6; // last KV tile this warp computes

  const int rl = lane >> 3;
  const int cs = (lane & 7) ^ rl;  // pre-swizzled source chunk

  auto stage = [&](int kv, int b) {
#pragma unroll
    for (int i = 0; i < 2; ++i) {
      const int r = (i * 4 + wave) * 8 + rl;
      gload_lds16(Kg + (size_t)(kv * 64 + r) * LDQK + h * D_HEAD + cs * 8,
                  &Ks[b][(i * 4 + wave) * 512]);
      gload_lds16(Vt + (size_t)(h * D_HEAD + r) * L_SEQ + kv * 64 + cs * 8,
                  &Vs[b][(i * 4 + wave) * 512]);
    }
  };

  stage(0, 0);

  // Q B-fragments (scale*log2e pre-folded by GEMM epilogue)
  bf16x8 qf[4];
  {
    const __bf16* qp = Q + (size_t)q * LDQK + h * D_HEAD + hl * 8;
#pragma unroll
    for (int s = 0; s < 4; ++s) qf[s] = *(const bf16x8*)(qp + s * 16);
  }

  f32x16 acc0 = {}, acc1 = {};  // O^T[d][q], d-tiles 0/1
  float m = -1e30f, lsum = 0.f;

  int cur = 0;
  for (int kv = 0; kv < nt; ++kv) {
    if (kv + 1 < nt) {
      stage(kv + 1, cur ^ 1);
      asm volatile("s_waitcnt vmcnt(4)" ::: "memory");
    } else {
      asm volatile("s_waitcnt vmcnt(0)" ::: "memory");
    }
    __builtin_amdgcn_sched_barrier(0);
    __builtin_amdgcn_s_barrier();
    __builtin_amdgcn_sched_barrier(0);

    if (kv <= kvmax_w) {
      char* const KsB = (char*)&Ks[cur][0];
      char* const VsB = (char*)&Vs[cur][0];

      // S^T = K . Q^T : lane holds q=l31, key rows kr(reg)+{0,32}
      f32x16 st0 = {}, st1 = {};
      __builtin_amdgcn_s_setprio(1);
#pragma unroll
      for (int s = 0; s < 4; ++s) {
        const int ch = s * 2 + hl;
        bf16x8 a0 = *(const bf16x8*)(KsB + l31 * 128 + ((ch ^ (l31 & 7)) << 4));
        bf16x8 a1 = *(const bf16x8*)(KsB + (32 + l31) * 128 + ((ch ^ (l31 & 7)) << 4));
        st0 = __builtin_amdgcn_mfma_f32_32x32x16_bf16(a0, qf[s], st0, 0, 0, 0);
        st1 = __builtin_amdgcn_mfma_f32_32x32x16_bf16(a1, qf[s], st1, 0, 0, 0);
      }
      __builtin_amdgcn_s_setprio(0);

      // causal mask: only the (always-partial) last tile of this warp
      if (kv == kvmax_w) {
#pragma unroll
        for (int r = 0; r < 16; ++r) {
          const int kr = (r & 3) + 8 * (r >> 2) + 4 * hl;
          const int k0 = kv * 64 + kr;
          st0[r] = (k0 <= q) ? st0[r] : -1e30f;
          st1[r] = (k0 + 32 <= q) ? st1[r] : -1e30f;
        }
      }

      // row max: in-lane tree + one cross-half swap
      float t[16];
#pragma unroll
      for (int r = 0; r < 16; ++r) t[r] = fmaxf(st0[r], st1[r]);
#pragma unroll
      for (int w = 8; w > 0; w >>= 1)
#pragma unroll
        for (int r = 0; r < w; ++r) t[r] = fmaxf(t[r], t[r + w]);
      float mx = fmaxf(t[0], __shfl_xor(t[0], 32, 64));
      const float mnew = fmaxf(m, mx);
      const float corr = exp2f(m - mnew);
      m = mnew;

      // exp2 + row sum
#pragma unroll
      for (int r = 0; r < 16; ++r) {
        st0[r] = exp2f(st0[r] - m);
        st1[r] = exp2f(st1[r] - m);
      }
      float sm[16];
#pragma unroll
      for (int r = 0; r < 16; ++r) sm[r] = st0[r] + st1[r];
#pragma unroll
      for (int w = 8; w > 0; w >>= 1)
#pragma unroll
        for (int r = 0; r < w; ++r) sm[r] = sm[r] + sm[r + w];
      float sl = sm[0] + __shfl_xor(sm[0], 32, 64);
      lsum = lsum * corr + sl;
      acc0 *= corr;
      acc1 *= corr;

      // P -> bf16 pk words (pairs of consecutive keys)
      u32 w0[8], w1[8];
#pragma unroll
      for (int i = 0; i < 8; ++i) {
        asm("v_cvt_pk_bf16_f32 %0, %1, %2" : "=v"(w0[i]) : "v"(st0[2 * i]), "v"(st0[2 * i + 1]));
        asm("v_cvt_pk_bf16_f32 %0, %1, %2" : "=v"(w1[i]) : "v"(st1[2 * i]), "v"(st1[2 * i + 1]));
      }
      // cross-half exchange: one shfl serves both directions
      u32 e0a = (u32)__shfl_xor((int)(hl ? w0[0] : w0[2]), 32, 64);
      u32 e0b = (u32)__shfl_xor((int)(hl ? w0[1] : w0[3]), 32, 64);
      u32 e0c = (u32)__shfl_xor((int)(hl ? w0[4] : w0[6]), 32, 64);
      u32 e0d = (u32)__shfl_xor((int)(hl ? w0[5] : w0[7]), 32, 64);
      u32 e1a = (u32)__shfl_xor((int)(hl ? w1[0] : w1[2]), 32, 64);
      u32 e1b = (u32)__shfl_xor((int)(hl ? w1[1] : w1[3]), 32, 64);
      u32 e1c = (u32)__shfl_xor((int)(hl ? w1[4] : w1[6]), 32, 64);
      u32 e1d = (u32)__shfl_xor((int)(hl ? w1[5] : w1[7]), 32, 64);
      u32x4 f0 = hl ? (u32x4){e0a, e0b, w0[2], w0[3]} : (u32x4){w0[0], w0[1], e0a, e0b};
      u32x4 f1 = hl ? (u32x4){e0c, e0d, w0[6], w0[7]} : (u32x4){w0[4], w0[5], e0c, e0d};
      u32x4 f2 = hl ? (u32x4){e1a, e1b, w1[2], w1[3]} : (u32x4){w1[0], w1[1], e1a, e1b};
      u32x4 f3 = hl ? (u32x4){e1c, e1d, w1[6], w1[7]} : (u32x4){w1[4], w1[5], e1c, e1d};
      bf16x8 pb0 = __builtin_bit_cast(bf16x8, f0);
      bf16x8 pb1 = __builtin_bit_cast(bf16x8, f1);
      bf16x8 pb2 = __builtin_bit_cast(bf16x8, f2);
      bf16x8 pb3 = __builtin_bit_cast(bf16x8, f3);

      // O^T += V^T . P^T
      __builtin_amdgcn_s_setprio(1);
#pragma unroll
      for (int s = 0; s < 4; ++s) {
        const bf16x8 pb = (s == 0) ? pb0 : (s == 1) ? pb1 : (s == 2) ? pb2 : pb3;
        const int ch = s * 2 + hl;
        bf16x8 va0 = *(const bf16x8*)(VsB + l31 * 128 + ((ch ^ (l31 & 7)) << 4));
        bf16x8 va1 = *(const bf16x8*)(VsB + (32 + l31) * 128 + ((ch ^ (l31 & 7)) << 4));
        acc0 = __builtin_amdgcn_mfma_f32_32x32x16_bf16(va0, pb, acc0, 0, 0, 0);
        acc1 = __builtin_amdgcn_mfma_f32_32x32x16_bf16(va1, pb, acc1, 0, 0, 0);
      }
      __builtin_amdgcn_s_setprio(0);
    }

    __builtin_amdgcn_sched_barrier(0);
    __builtin_amdgcn_s_barrier();
    __builtin_amdgcn_sched_barrier(0);
    cur ^= 1;
  }

  // epilogue: normalize, transpose O^T->O via per-warp swizzled LDS, store
  const float rinv = 1.0f / lsum;
  char* const Po = (char*)&Ks[0][0] + wave * 4096;  // 32q x 64d bf16 = 4KB/warp
#pragma unroll
  for (int dt = 0; dt < 2; ++dt) {
#pragma unroll
    for (int i = 0; i < 8; ++i) {
      const int r = 2 * i;
      const int d = dt * 32 + (r & 3) + 8 * (r >> 2) + 4 * hl;
      float lo = (dt ? acc1[r] : acc0[r]) * rinv;
      float hi = (dt ? acc1[r + 1] : acc0[r + 1]) * rinv;
      u32 wv;
      asm("v_cvt_pk_bf16_f32 %0, %1, %2" : "=v"(wv) : "v"(lo), "v"(hi));
      *(u32*)(Po + l31 * 128 + (((d >> 3) ^ (l31 & 7)) << 4) + (d & 7) * 2) = wv;
    }
  }
  asm volatile("s_waitcnt lgkmcnt(0)" ::: "memory");
  __builtin_amdgcn_sched_barrier(0);
#pragma unroll
  for (int j = 0; j < 4; ++j) {
    const int qr = lane >> 1;
    const int c = (lane & 1) * 4 + j;
    bf16x8 ov = *(const bf16x8*)(Po + qr * 128 + ((c ^ (qr & 7)) << 4));
    *(bf16x8*)(O + (size_t)(qbase + qr) * C_DIM + h * D_HEAD + c * 8) = ov;
  }
}

extern "C" void kernel_launch(void* const* d_in, const int* in_sizes, int n_in,
                              void* d_out, int out_size, void* d_ws, size_t ws_size,
                              hipStream_t stream) {
  const float* x = (const float*)d_in[0];
  const float* Wq = (const float*)d_in[1];
  const float* Wk = (const float*)d_in[2];
  const float* Wv = (const float*)d_in[3];
  const float* Wo = (const float*)d_in[4];
  float* out = (float*)d_out;

  char* ws = (char*)d_ws;
  __bf16* xb    = (__bf16*)(ws);                 // [0,8M) x bf16; reused as Ab
  __bf16* WqkvT = (__bf16*)(ws + (8u << 20));    // [8M,16M) WqT,WkT,WvT,WoT
  __bf16* QKb   = (__bf16*)(ws + (16u << 20));   // [16M,32M) 4096x2048
  __bf16* Vtb   = (__bf16*)(ws + (32u << 20));   // [32M,40M) 1024x4096
  __bf16* WvT   = WqkvT + (size_t)2 * 1048576;
  __bf16* WoT   = WqkvT + (size_t)3 * 1048576;
  __bf16* Ab    = xb;

  cvt_f32_bf16<<<4096, 256, 0, stream>>>(x, xb);

  transpose_cvt4<<<dim3(32, 32, 4), dim3(32, 8), 0, stream>>>(Wq, Wk, Wv, Wo, WqkvT);

  // fused QK projection; Q columns pre-scaled by 0.125*log2(e)
  gemm_bt<true><<<dim3(32, 16), 256, 0, stream>>>(
      xb, WqkvT, QKb, L_SEQ, LDQK, C_DIM, SC_LOG2E, 1024);

  // V^T projection: Vt[c][l] = sum_k WvT[c][k] * xb[l][k]
  gemm_bt<true><<<dim3(8, 32), 256, 0, stream>>>(
      WvT, xb, Vtb, C_DIM, L_SEQ, C_DIM, 1.0f, 0);

  attn_fwd<<<512, 256, 0, stream>>>(QKb, QKb + 1024, Vtb, Ab);

  gemm_bt<false><<<dim3(32, 8), 256, 0, stream>>>(
      Ab, WoT, out, L_SEQ, C_DIM, C_DIM, 1.0f, 0);
}

// Round 8
// 275.333 us; speedup vs baseline: 1.0656x; 1.0099x over previous
//
#include <hip/hip_runtime.h>

// Problem constants (B=1)
#define L_SEQ 4096
#define C_DIM 1024
#define H_NUM 16
#define D_HEAD 64
#define LDQK 2048

typedef __bf16 bf16x8 __attribute__((ext_vector_type(8)));
typedef __bf16 bf16x4 __attribute__((ext_vector_type(4)));
typedef float f32x4 __attribute__((ext_vector_type(4)));
typedef float f32x16 __attribute__((ext_vector_type(16)));
typedef unsigned int u32;
typedef u32 u32x4 __attribute__((ext_vector_type(4)));

#define AS1 __attribute__((address_space(1)))
#define AS3 __attribute__((address_space(3)))

#define SC_LOG2E 0.1803368801111204f  // 0.125 * log2(e)

__device__ inline __bf16 f2bf(float f) {
  unsigned u = __builtin_bit_cast(unsigned, f);
  u = (u + 0x7fffu + ((u >> 16) & 1u)) >> 16;
  unsigned short s = (unsigned short)u;
  return __builtin_bit_cast(__bf16, s);
}

__device__ inline void gload_lds16(const __bf16* g, __bf16* l) {
  __builtin_amdgcn_global_load_lds((const AS1 void*)g, (AS3 void*)l, 16, 0, 0);
}

// ------------- prep: x fp32->bf16 (blocks 0..4095) + 4x W^T cvt (4096..8191) --
__global__ __launch_bounds__(256) void prep(const float* __restrict__ x,
                                            const float* __restrict__ W0,
                                            const float* __restrict__ W1,
                                            const float* __restrict__ W2,
                                            const float* __restrict__ W3,
                                            __bf16* __restrict__ xb,
                                            __bf16* __restrict__ Wt) {
  __shared__ float t[32][33];
  int id = blockIdx.x;
  if (id < 4096) {
    int i = (id * 256 + threadIdx.x) * 4;
    float4 v = *(const float4*)(x + i);
    bf16x4 o = {f2bf(v.x), f2bf(v.y), f2bf(v.z), f2bf(v.w)};
    *(bf16x4*)(xb + i) = o;
    return;
  }
  id -= 4096;
  const int z = id >> 10;
  const int rem = id & 1023;
  const float* W = (z == 0) ? W0 : (z == 1) ? W1 : (z == 2) ? W2 : W3;
  __bf16* dst = Wt + (size_t)z * 1048576;
  const int tx = threadIdx.x & 31, ty = threadIdx.x >> 5;
  const int c0 = (rem & 31) * 32, r0 = (rem >> 5) * 32;
#pragma unroll
  for (int k = 0; k < 4; ++k)
    t[ty + k * 8][tx] = W[(size_t)(r0 + ty + k * 8) * C_DIM + c0 + tx];
  __syncthreads();
#pragma unroll
  for (int k = 0; k < 4; ++k)
    dst[(size_t)(c0 + ty + k * 8) * C_DIM + r0 + tx] = f2bf(t[tx][ty + k * 8]);
}

// ---- fused QK-projection + V^T-projection (independent jobs, one launch) ----
// blocks 0..511:  QKb[4096x2048] = xb @ WqkT^T   (Q cols scaled by SC_LOG2E)
// blocks 512..767: Vtb[1024x4096] = WvT @ xb^T
__global__ __launch_bounds__(256) void gemm_qkv(const __bf16* __restrict__ xb,
                                                const __bf16* __restrict__ WqkT,
                                                const __bf16* __restrict__ WvT,
                                                __bf16* __restrict__ QKb,
                                                __bf16* __restrict__ Vtb) {
  __shared__ __bf16 As[128 * 32];
  __shared__ __bf16 Bs[128 * 32];
  int g = blockIdx.x;
  const __bf16 *A, *Bt;
  __bf16* C;
  int N;
  size_t arow0, brow0;
  float esc;
  if (g < 512) {
    A = xb; Bt = WqkT; C = QKb; N = 2048;
    arow0 = (size_t)(g & 31) * 128;
    brow0 = (size_t)(g >> 5) * 128;
    esc = ((int)brow0 < 1024) ? SC_LOG2E : 1.0f;
  } else {
    g -= 512;
    A = WvT; Bt = xb; C = Vtb; N = 4096;
    arow0 = (size_t)(g & 7) * 128;
    brow0 = (size_t)(g >> 3) * 128;
    esc = 1.0f;
  }
  const int K = 1024;

  const int tid = threadIdx.x;
  const int lane = tid & 63;
  const int wave = tid >> 6;
  const int wm = wave >> 1, wn = wave & 1;
  const int c16 = lane & 15, g4 = lane >> 4;
  const int srow = lane >> 2, scol = (lane & 3) * 8;

  f32x4 acc[4][4] = {};

  for (int kt = 0; kt < K; kt += 32) {
#pragma unroll
    for (int i = 0; i < 2; ++i) {
      const int row = i * 64 + wave * 16 + srow;
      gload_lds16(A + (arow0 + row) * K + kt + scol, As + (i * 64 + wave * 16) * 32);
      gload_lds16(Bt + (brow0 + row) * K + kt + scol, Bs + (i * 64 + wave * 16) * 32);
    }
    __syncthreads();
    bf16x8 af[4], bfr[4];
#pragma unroll
    for (int mi = 0; mi < 4; ++mi)
      af[mi] = *(const bf16x8*)(As + (wm * 64 + mi * 16 + c16) * 32 + g4 * 8);
#pragma unroll
    for (int ni = 0; ni < 4; ++ni)
      bfr[ni] = *(const bf16x8*)(Bs + (wn * 64 + ni * 16 + c16) * 32 + g4 * 8);
#pragma unroll
    for (int mi = 0; mi < 4; ++mi)
#pragma unroll
      for (int ni = 0; ni < 4; ++ni)
        acc[mi][ni] = __builtin_amdgcn_mfma_f32_16x16x32_bf16(af[mi], bfr[ni], acc[mi][ni], 0, 0, 0);
    __syncthreads();
  }

#pragma unroll
  for (int mi = 0; mi < 4; ++mi)
#pragma unroll
    for (int ni = 0; ni < 4; ++ni)
#pragma unroll
      for (int i = 0; i < 4; ++i) {
        size_t row = arow0 + wm * 64 + mi * 16 + g4 * 4 + i;
        size_t col = brow0 + wn * 64 + ni * 16 + c16;
        C[row * N + col] = f2bf(acc[mi][ni][i] * esc);
      }
}

// ---------------- GEMM: C(MxN) = A(MxK,bf16) * Bt(NxK,bf16)^T ----------------
template <bool OUT_BF16>
__global__ __launch_bounds__(256) void gemm_bt(const __bf16* __restrict__ A,
                                               const __bf16* __restrict__ Bt,
                                               void* __restrict__ Cp,
                                               int M, int N, int K,
                                               float cscale, int scale_ncols) {
  __shared__ __bf16 As[128 * 32];
  __shared__ __bf16 Bs[128 * 32];
  const int tid = threadIdx.x;
  const int lane = tid & 63;
  const int wave = tid >> 6;
  const int wm = wave >> 1, wn = wave & 1;
  const int c16 = lane & 15, g4 = lane >> 4;
  const int srow = lane >> 2, scol = (lane & 3) * 8;

  f32x4 acc[4][4] = {};

  const size_t arow0 = (size_t)blockIdx.x * 128;
  const size_t brow0 = (size_t)blockIdx.y * 128;

  for (int kt = 0; kt < K; kt += 32) {
#pragma unroll
    for (int i = 0; i < 2; ++i) {
      const int row = i * 64 + wave * 16 + srow;
      gload_lds16(A + (arow0 + row) * K + kt + scol, As + (i * 64 + wave * 16) * 32);
      gload_lds16(Bt + (brow0 + row) * K + kt + scol, Bs + (i * 64 + wave * 16) * 32);
    }
    __syncthreads();
    bf16x8 af[4], bfr[4];
#pragma unroll
    for (int mi = 0; mi < 4; ++mi)
      af[mi] = *(const bf16x8*)(As + (wm * 64 + mi * 16 + c16) * 32 + g4 * 8);
#pragma unroll
    for (int ni = 0; ni < 4; ++ni)
      bfr[ni] = *(const bf16x8*)(Bs + (wn * 64 + ni * 16 + c16) * 32 + g4 * 8);
#pragma unroll
    for (int mi = 0; mi < 4; ++mi)
#pragma unroll
      for (int ni = 0; ni < 4; ++ni)
        acc[mi][ni] = __builtin_amdgcn_mfma_f32_16x16x32_bf16(af[mi], bfr[ni], acc[mi][ni], 0, 0, 0);
    __syncthreads();
  }

  const float esc = ((int)brow0 < scale_ncols) ? cscale : 1.0f;
#pragma unroll
  for (int mi = 0; mi < 4; ++mi)
#pragma unroll
    for (int ni = 0; ni < 4; ++ni)
#pragma unroll
      for (int i = 0; i < 4; ++i) {
        size_t row = arow0 + wm * 64 + mi * 16 + g4 * 4 + i;
        size_t col = brow0 + wn * 64 + ni * 16 + c16;
        if (OUT_BF16)
          ((__bf16*)Cp)[row * N + col] = f2bf(acc[mi][ni][i] * esc);
        else
          ((float*)Cp)[row * N + col] = acc[mi][ni][i];
      }
}

// --------- causal flash attention, 32x32 swapped-QK^T, sequential pair -------
// grid 256 x 256 threads: block (p,h) handles q-tiles {31-p, p} (128 rows each)
// SEQUENTIALLY => exactly 66 staged KV tiles per block: structural balance
// independent of block->CU mapping. 4 waves x 32 q rows. 3-deep KV buffer,
// ONE barrier per iteration, counted vmcnt(8). Lane holds full P row (T12).
__global__ __launch_bounds__(256, 1) void attn_fwd(const __bf16* __restrict__ Q,
                                                   const __bf16* __restrict__ Kg,
                                                   const __bf16* __restrict__ Vt,
                                                   __bf16* __restrict__ O) {
  const int bid = blockIdx.x;
  const int h = bid & 15;
  const int p = bid >> 4;           // 0..15
  const int qtA = 31 - p, qtB = p;
  const int ntA = 2 * qtA + 2;      // 34..64
  const int NT = 66;                // ntA + ntB

  __shared__ __bf16 Ks[3][64 * 64];  // [key][d], XOR-swizzled 16B chunks (24KB)
  __shared__ __bf16 Vs[3][64 * 64];  // [d][key], XOR-swizzled (24KB)
  __shared__ __bf16 PoS[4][2048];    // per-warp O-transpose buffers (16KB)

  const int tid = threadIdx.x;
  const int lane = tid & 63;
  const int wave = tid >> 6;
  const int l31 = lane & 31;
  const int hl = lane >> 5;
  const int rl = lane >> 3;
  const int cs = (lane & 7) ^ rl;  // pre-swizzled source chunk

  // stage KV tile for flat index idx into buffer b
  auto stage = [&](int idx, int b) {
    const int kv = (idx < ntA) ? idx : idx - ntA;
#pragma unroll
    for (int i = 0; i < 2; ++i) {
      const int r = (i * 4 + wave) * 8 + rl;
      gload_lds16(Kg + (size_t)(kv * 64 + r) * LDQK + h * D_HEAD + cs * 8,
                  &Ks[b][(i * 4 + wave) * 512]);
      gload_lds16(Vt + (size_t)(h * D_HEAD + r) * L_SEQ + kv * 64 + cs * 8,
                  &Vs[b][(i * 4 + wave) * 512]);
    }
  };

  // Q fragments for BOTH segments up front (8 dwordx4; drained by 1st vmcnt)
  int qbase = qtA * 128 + wave * 32;
  bf16x8 qf[4], qfB[4];
  {
    const __bf16* qp = Q + (size_t)(qbase + l31) * LDQK + h * D_HEAD + hl * 8;
#pragma unroll
    for (int s = 0; s < 4; ++s) qf[s] = *(const bf16x8*)(qp + s * 16);
    const __bf16* qp2 = Q + (size_t)(qtB * 128 + wave * 32 + l31) * LDQK + h * D_HEAD + hl * 8;
#pragma unroll
    for (int s = 0; s < 4; ++s) qfB[s] = *(const bf16x8*)(qp2 + s * 16);
  }

  stage(0, 0);
  stage(1, 1);

  int kvmax_w = 2 * qtA + (wave >> 1);
  int q = qbase + l31;

  f32x16 acc0 = {}, acc1 = {};
  float m = -1e30f, lsum = 0.f;
  int bc = 0;  // compute buffer = idx % 3

  // warp-local epilogue: normalize + transpose O^T->O via PoS + store
  auto epilogue = [&]() {
    const float rinv = 1.0f / lsum;
    char* const Po = (char*)&PoS[wave][0];
#pragma unroll
    for (int dt = 0; dt < 2; ++dt) {
#pragma unroll
      for (int i = 0; i < 8; ++i) {
        const int r = 2 * i;
        const int d = dt * 32 + (r & 3) + 8 * (r >> 2) + 4 * hl;
        float lo = (dt ? acc1[r] : acc0[r]) * rinv;
        float hi = (dt ? acc1[r + 1] : acc0[r + 1]) * rinv;
        u32 wv;
        asm("v_cvt_pk_bf16_f32 %0, %1, %2" : "=v"(wv) : "v"(lo), "v"(hi));
        *(u32*)(Po + l31 * 128 + (((d >> 3) ^ (l31 & 7)) << 4) + (d & 7) * 2) = wv;
      }
    }
    asm volatile("s_waitcnt lgkmcnt(0)" ::: "memory");
    __builtin_amdgcn_sched_barrier(0);
#pragma unroll
    for (int j = 0; j < 4; ++j) {
      const int qr = lane >> 1;
      const int c = (lane & 1) * 4 + j;
      bf16x8 ov = *(const bf16x8*)(Po + qr * 128 + ((c ^ (qr & 7)) << 4));
      *(bf16x8*)(O + (size_t)(qbase + qr) * C_DIM + h * D_HEAD + c * 8) = ov;
    }
  };

  for (int idx = 0; idx < NT; ++idx) {
    __builtin_amdgcn_sched_barrier(0);
    __builtin_amdgcn_s_barrier();
    __builtin_amdgcn_sched_barrier(0);

    if (idx + 2 < NT) {
      int bs = bc + 2; if (bs >= 3) bs -= 3;
      stage(idx + 2, bs);
      asm volatile("s_waitcnt vmcnt(8)" ::: "memory");
    } else if (idx + 2 == NT) {
      asm volatile("s_waitcnt vmcnt(4)" ::: "memory");
    } else {
      asm volatile("s_waitcnt vmcnt(0)" ::: "memory");
    }
    __builtin_amdgcn_sched_barrier(0);

    const int kvl = (idx < ntA) ? idx : idx - ntA;

    if (kvl <= kvmax_w) {
      char* const KsB = (char*)&Ks[bc][0];
      char* const VsB = (char*)&Vs[bc][0];

      // S^T = K . Q^T : lane holds q row; key rows kr(reg)+{0,32}
      f32x16 st0 = {}, st1 = {};
      __builtin_amdgcn_s_setprio(1);
#pragma unroll
      for (int s = 0; s < 4; ++s) {
        const int ch = s * 2 + hl;
        bf16x8 a0 = *(const bf16x8*)(KsB + l31 * 128 + ((ch ^ (l31 & 7)) << 4));
        bf16x8 a1 = *(const bf16x8*)(KsB + (32 + l31) * 128 + ((ch ^ (l31 & 7)) << 4));
        st0 = __builtin_amdgcn_mfma_f32_32x32x16_bf16(a0, qf[s], st0, 0, 0, 0);
        st1 = __builtin_amdgcn_mfma_f32_32x32x16_bf16(a1, qf[s], st1, 0, 0, 0);
      }
      __builtin_amdgcn_s_setprio(0);

      if (kvl == kvmax_w) {  // diagonal tile
#pragma unroll
        for (int r = 0; r < 16; ++r) {
          const int kr = (r & 3) + 8 * (r >> 2) + 4 * hl;
          const int k0 = kvl * 64 + kr;
          st0[r] = (k0 <= q) ? st0[r] : -1e30f;
          st1[r] = (k0 + 32 <= q) ? st1[r] : -1e30f;
        }
      }

      // row max: in-lane tree + one cross-half swap
      float t[16];
#pragma unroll
      for (int r = 0; r < 16; ++r) t[r] = fmaxf(st0[r], st1[r]);
#pragma unroll
      for (int w = 8; w > 0; w >>= 1)
#pragma unroll
        for (int r = 0; r < w; ++r) t[r] = fmaxf(t[r], t[r + w]);
      float mx = fmaxf(t[0], __shfl_xor(t[0], 32, 64));
      const float mnew = fmaxf(m, mx);
      const float corr = exp2f(m - mnew);
      m = mnew;

      // exp2 + row sum
#pragma unroll
      for (int r = 0; r < 16; ++r) {
        st0[r] = exp2f(st0[r] - m);
        st1[r] = exp2f(st1[r] - m);
      }
      float sm[16];
#pragma unroll
      for (int r = 0; r < 16; ++r) sm[r] = st0[r] + st1[r];
#pragma unroll
      for (int w = 8; w > 0; w >>= 1)
#pragma unroll
        for (int r = 0; r < w; ++r) sm[r] = sm[r] + sm[r + w];
      float sl = sm[0] + __shfl_xor(sm[0], 32, 64);
      lsum = lsum * corr + sl;
      acc0 *= corr;
      acc1 *= corr;

      // P -> bf16 pk words, cross-half exchange
      u32 w0[8], w1[8];
#pragma unroll
      for (int i = 0; i < 8; ++i) {
        asm("v_cvt_pk_bf16_f32 %0, %1, %2" : "=v"(w0[i]) : "v"(st0[2 * i]), "v"(st0[2 * i + 1]));
        asm("v_cvt_pk_bf16_f32 %0, %1, %2" : "=v"(w1[i]) : "v"(st1[2 * i]), "v"(st1[2 * i + 1]));
      }
      u32 e0a = (u32)__shfl_xor((int)(hl ? w0[0] : w0[2]), 32, 64);
      u32 e0b = (u32)__shfl_xor((int)(hl ? w0[1] : w0[3]), 32, 64);
      u32 e0c = (u32)__shfl_xor((int)(hl ? w0[4] : w0[6]), 32, 64);
      u32 e0d = (u32)__shfl_xor((int)(hl ? w0[5] : w0[7]), 32, 64);
      u32 e1a = (u32)__shfl_xor((int)(hl ? w1[0] : w1[2]), 32, 64);
      u32 e1b = (u32)__shfl_xor((int)(hl ? w1[1] : w1[3]), 32, 64);
      u32 e1c = (u32)__shfl_xor((int)(hl ? w1[4] : w1[6]), 32, 64);
      u32 e1d = (u32)__shfl_xor((int)(hl ? w1[5] : w1[7]), 32, 64);
      u32x4 f0 = hl ? (u32x4){e0a, e0b, w0[2], w0[3]} : (u32x4){w0[0], w0[1], e0a, e0b};
      u32x4 f1 = hl ? (u32x4){e0c, e0d, w0[6], w0[7]} : (u32x4){w0[4], w0[5], e0c, e0d};
      u32x4 f2 = hl ? (u32x4){e1a, e1b, w1[2], w1[3]} : (u32x4){w1[0], w1[1], e1a, e1b};
      u32x4 f3 = hl ? (u32x4){e1c, e1d, w1[6], w1[7]} : (u32x4){w1[4], w1[5], e1c, e1d};
      bf16x8 pb0 = __builtin_bit_cast(bf16x8, f0);
      bf16x8 pb1 = __builtin_bit_cast(bf16x8, f1);
      bf16x8 pb2 = __builtin_bit_cast(bf16x8, f2);
      bf16x8 pb3 = __builtin_bit_cast(bf16x8, f3);

      // O^T += V^T . P^T
      __builtin_amdgcn_s_setprio(1);
#pragma unroll
      for (int s = 0; s < 4; ++s) {
        const bf16x8 pb = (s == 0) ? pb0 : (s == 1) ? pb1 : (s == 2) ? pb2 : pb3;
        const int ch = s * 2 + hl;
        bf16x8 va0 = *(const bf16x8*)(VsB + l31 * 128 + ((ch ^ (l31 & 7)) << 4));
        bf16x8 va1 = *(const bf16x8*)(VsB + (32 + l31) * 128 + ((ch ^ (l31 & 7)) << 4));
        acc0 = __builtin_amdgcn_mfma_f32_32x32x16_bf16(va0, pb, acc0, 0, 0, 0);
        acc1 = __builtin_amdgcn_mfma_f32_32x32x16_bf16(va1, pb, acc1, 0, 0, 0);
      }
      __builtin_amdgcn_s_setprio(0);
    }

    if (idx == ntA - 1) {
      // finish segment A, switch to segment B
      epilogue();
      qbase = qtB * 128 + wave * 32;
      q = qbase + l31;
      kvmax_w = 2 * qtB + (wave >> 1);
#pragma unroll
      for (int s = 0; s < 4; ++s) qf[s] = qfB[s];
      acc0 = (f32x16){};
      acc1 = (f32x16){};
      m = -1e30f;
      lsum = 0.f;
    }

    bc = (bc + 1 == 3) ? 0 : bc + 1;
  }

  epilogue();
}

extern "C" void kernel_launch(void* const* d_in, const int* in_sizes, int n_in,
                              void* d_out, int out_size, void* d_ws, size_t ws_size,
                              hipStream_t stream) {
  const float* x = (const float*)d_in[0];
  const float* Wq = (const float*)d_in[1];
  const float* Wk = (const float*)d_in[2];
  const float* Wv = (const float*)d_in[3];
  const float* Wo = (const float*)d_in[4];
  float* out = (float*)d_out;

  char* ws = (char*)d_ws;
  __bf16* xb    = (__bf16*)(ws);                 // [0,8M) x bf16; reused as Ab
  __bf16* WqkvT = (__bf16*)(ws + (8u << 20));    // [8M,16M) WqT,WkT,WvT,WoT
  __bf16* QKb   = (__bf16*)(ws + (16u << 20));   // [16M,32M) 4096x2048
  __bf16* Vtb   = (__bf16*)(ws + (32u << 20));   // [32M,40M) 1024x4096
  __bf16* WvT   = WqkvT + (size_t)2 * 1048576;
  __bf16* WoT   = WqkvT + (size_t)3 * 1048576;
  __bf16* Ab    = xb;

  prep<<<8192, 256, 0, stream>>>(x, Wq, Wk, Wv, Wo, xb, WqkvT);

  gemm_qkv<<<768, 256, 0, stream>>>(xb, WqkvT, WvT, QKb, Vtb);

  attn_fwd<<<256, 256, 0, stream>>>(QKb, QKb + 1024, Vtb, Ab);

  gemm_bt<false><<<dim3(32, 8), 256, 0, stream>>>(
      Ab, WoT, out, L_SEQ, C_DIM, C_DIM, 1.0f, 0);
}

// Round 9
// 241.234 us; speedup vs baseline: 1.2163x; 1.1414x over previous
//
#include <hip/hip_runtime.h>

// Problem constants (B=1)
#define L_SEQ 4096
#define C_DIM 1024
#define H_NUM 16
#define D_HEAD 64
#define LDQK 2048

typedef __bf16 bf16x8 __attribute__((ext_vector_type(8)));
typedef __bf16 bf16x4 __attribute__((ext_vector_type(4)));
typedef float f32x4 __attribute__((ext_vector_type(4)));
typedef float f32x16 __attribute__((ext_vector_type(16)));
typedef unsigned int u32;
typedef u32 u32x4 __attribute__((ext_vector_type(4)));

#define AS1 __attribute__((address_space(1)))
#define AS3 __attribute__((address_space(3)))

#define SC_LOG2E 0.1803368801111204f  // 0.125 * log2(e)

__device__ inline __bf16 f2bf(float f) {
  unsigned u = __builtin_bit_cast(unsigned, f);
  u = (u + 0x7fffu + ((u >> 16) & 1u)) >> 16;
  unsigned short s = (unsigned short)u;
  return __builtin_bit_cast(__bf16, s);
}

__device__ inline void gload_lds16(const __bf16* g, __bf16* l) {
  __builtin_amdgcn_global_load_lds((const AS1 void*)g, (AS3 void*)l, 16, 0, 0);
}

// ------------- prep: x fp32->bf16 (blocks 0..4095) + 4x W^T cvt (4096..8191) --
__global__ __launch_bounds__(256) void prep(const float* __restrict__ x,
                                            const float* __restrict__ W0,
                                            const float* __restrict__ W1,
                                            const float* __restrict__ W2,
                                            const float* __restrict__ W3,
                                            __bf16* __restrict__ xb,
                                            __bf16* __restrict__ Wt) {
  __shared__ float t[32][33];
  int id = blockIdx.x;
  if (id < 4096) {
    int i = (id * 256 + threadIdx.x) * 4;
    float4 v = *(const float4*)(x + i);
    bf16x4 o = {f2bf(v.x), f2bf(v.y), f2bf(v.z), f2bf(v.w)};
    *(bf16x4*)(xb + i) = o;
    return;
  }
  id -= 4096;
  const int z = id >> 10;
  const int rem = id & 1023;
  const float* W = (z == 0) ? W0 : (z == 1) ? W1 : (z == 2) ? W2 : W3;
  __bf16* dst = Wt + (size_t)z * 1048576;
  const int tx = threadIdx.x & 31, ty = threadIdx.x >> 5;
  const int c0 = (rem & 31) * 32, r0 = (rem >> 5) * 32;
#pragma unroll
  for (int k = 0; k < 4; ++k)
    t[ty + k * 8][tx] = W[(size_t)(r0 + ty + k * 8) * C_DIM + c0 + tx];
  __syncthreads();
#pragma unroll
  for (int k = 0; k < 4; ++k)
    dst[(size_t)(c0 + ty + k * 8) * C_DIM + r0 + tx] = f2bf(t[tx][ty + k * 8]);
}

// ---- fused QK-projection + V^T-projection (independent jobs, one launch) ----
// blocks 0..511:  QKb[4096x2048] = xb @ WqkT^T   (Q cols scaled by SC_LOG2E)
// blocks 512..767: Vtb[1024x4096] = WvT @ xb^T
__global__ __launch_bounds__(256) void gemm_qkv(const __bf16* __restrict__ xb,
                                                const __bf16* __restrict__ WqkT,
                                                const __bf16* __restrict__ WvT,
                                                __bf16* __restrict__ QKb,
                                                __bf16* __restrict__ Vtb) {
  __shared__ __bf16 As[128 * 32];
  __shared__ __bf16 Bs[128 * 32];
  int g = blockIdx.x;
  const __bf16 *A, *Bt;
  __bf16* C;
  int N;
  size_t arow0, brow0;
  float esc;
  if (g < 512) {
    A = xb; Bt = WqkT; C = QKb; N = 2048;
    arow0 = (size_t)(g & 31) * 128;
    brow0 = (size_t)(g >> 5) * 128;
    esc = ((int)brow0 < 1024) ? SC_LOG2E : 1.0f;
  } else {
    g -= 512;
    A = WvT; Bt = xb; C = Vtb; N = 4096;
    arow0 = (size_t)(g & 7) * 128;
    brow0 = (size_t)(g >> 3) * 128;
    esc = 1.0f;
  }
  const int K = 1024;

  const int tid = threadIdx.x;
  const int lane = tid & 63;
  const int wave = tid >> 6;
  const int wm = wave >> 1, wn = wave & 1;
  const int c16 = lane & 15, g4 = lane >> 4;
  const int srow = lane >> 2, scol = (lane & 3) * 8;

  f32x4 acc[4][4] = {};

  for (int kt = 0; kt < K; kt += 32) {
#pragma unroll
    for (int i = 0; i < 2; ++i) {
      const int row = i * 64 + wave * 16 + srow;
      gload_lds16(A + (arow0 + row) * K + kt + scol, As + (i * 64 + wave * 16) * 32);
      gload_lds16(Bt + (brow0 + row) * K + kt + scol, Bs + (i * 64 + wave * 16) * 32);
    }
    __syncthreads();
    bf16x8 af[4], bfr[4];
#pragma unroll
    for (int mi = 0; mi < 4; ++mi)
      af[mi] = *(const bf16x8*)(As + (wm * 64 + mi * 16 + c16) * 32 + g4 * 8);
#pragma unroll
    for (int ni = 0; ni < 4; ++ni)
      bfr[ni] = *(const bf16x8*)(Bs + (wn * 64 + ni * 16 + c16) * 32 + g4 * 8);
#pragma unroll
    for (int mi = 0; mi < 4; ++mi)
#pragma unroll
      for (int ni = 0; ni < 4; ++ni)
        acc[mi][ni] = __builtin_amdgcn_mfma_f32_16x16x32_bf16(af[mi], bfr[ni], acc[mi][ni], 0, 0, 0);
    __syncthreads();
  }

#pragma unroll
  for (int mi = 0; mi < 4; ++mi)
#pragma unroll
    for (int ni = 0; ni < 4; ++ni)
#pragma unroll
      for (int i = 0; i < 4; ++i) {
        size_t row = arow0 + wm * 64 + mi * 16 + g4 * 4 + i;
        size_t col = brow0 + wn * 64 + ni * 16 + c16;
        C[row * N + col] = f2bf(acc[mi][ni][i] * esc);
      }
}

// ---------------- GEMM: C(MxN) = A(MxK,bf16) * Bt(NxK,bf16)^T ----------------
template <bool OUT_BF16>
__global__ __launch_bounds__(256) void gemm_bt(const __bf16* __restrict__ A,
                                               const __bf16* __restrict__ Bt,
                                               void* __restrict__ Cp,
                                               int M, int N, int K,
                                               float cscale, int scale_ncols) {
  __shared__ __bf16 As[128 * 32];
  __shared__ __bf16 Bs[128 * 32];
  const int tid = threadIdx.x;
  const int lane = tid & 63;
  const int wave = tid >> 6;
  const int wm = wave >> 1, wn = wave & 1;
  const int c16 = lane & 15, g4 = lane >> 4;
  const int srow = lane >> 2, scol = (lane & 3) * 8;

  f32x4 acc[4][4] = {};

  const size_t arow0 = (size_t)blockIdx.x * 128;
  const size_t brow0 = (size_t)blockIdx.y * 128;

  for (int kt = 0; kt < K; kt += 32) {
#pragma unroll
    for (int i = 0; i < 2; ++i) {
      const int row = i * 64 + wave * 16 + srow;
      gload_lds16(A + (arow0 + row) * K + kt + scol, As + (i * 64 + wave * 16) * 32);
      gload_lds16(Bt + (brow0 + row) * K + kt + scol, Bs + (i * 64 + wave * 16) * 32);
    }
    __syncthreads();
    bf16x8 af[4], bfr[4];
#pragma unroll
    for (int mi = 0; mi < 4; ++mi)
      af[mi] = *(const bf16x8*)(As + (wm * 64 + mi * 16 + c16) * 32 + g4 * 8);
#pragma unroll
    for (int ni = 0; ni < 4; ++ni)
      bfr[ni] = *(const bf16x8*)(Bs + (wn * 64 + ni * 16 + c16) * 32 + g4 * 8);
#pragma unroll
    for (int mi = 0; mi < 4; ++mi)
#pragma unroll
      for (int ni = 0; ni < 4; ++ni)
        acc[mi][ni] = __builtin_amdgcn_mfma_f32_16x16x32_bf16(af[mi], bfr[ni], acc[mi][ni], 0, 0, 0);
    __syncthreads();
  }

  const float esc = ((int)brow0 < scale_ncols) ? cscale : 1.0f;
#pragma unroll
  for (int mi = 0; mi < 4; ++mi)
#pragma unroll
    for (int ni = 0; ni < 4; ++ni)
#pragma unroll
      for (int i = 0; i < 4; ++i) {
        size_t row = arow0 + wm * 64 + mi * 16 + g4 * 4 + i;
        size_t col = brow0 + wn * 64 + ni * 16 + c16;
        if (OUT_BF16)
          ((__bf16*)Cp)[row * N + col] = f2bf(acc[mi][ni][i] * esc);
        else
          ((float*)Cp)[row * N + col] = acc[mi][ni][i];
      }
}

// ---------------- causal flash attention, 32x32 swapped-QK^T ------------------
// grid 512 x 256 threads (2 blocks/CU): 32 q-tiles of 128 rows x 16 heads.
// 4 waves x 32 q rows; lane holds full P row in regs (T12). 3-deep KV LDS
// buffer with ONE barrier per iteration: {stage(n+1); vmcnt(4); barrier;
// compute(n)} — each wave drains its stage(n) before the barrier, so after
// the barrier all waves' portions of buf n are visible (race-free).
__global__ __launch_bounds__(256, 2) void attn_fwd(const __bf16* __restrict__ Q,
                                                   const __bf16* __restrict__ Kg,
                                                   const __bf16* __restrict__ Vt,
                                                   __bf16* __restrict__ O) {
  const int bid = blockIdx.x;
  const int h = bid & 15;
  const int g = (bid >> 4) & 15;
  const int qt = (bid < 256) ? (31 - g) : g;
  const int nt = 2 * qt + 2;

  __shared__ __bf16 Ks[3][64 * 64];  // [key][d], XOR-swizzled (24KB)
  __shared__ __bf16 Vs[3][64 * 64];  // [d][key], XOR-swizzled (24KB)
  __shared__ __bf16 PoS[4][2048];    // per-warp O-transpose buffers (16KB)

  const int tid = threadIdx.x;
  const int lane = tid & 63;
  const int wave = tid >> 6;
  const int l31 = lane & 31;
  const int hl = lane >> 5;
  const int qbase = qt * 128 + wave * 32;
  const int q = qbase + l31;             // this lane's q row
  const int kvmax_w = (qbase + 31) >> 6; // last KV tile this warp computes

  const int rl = lane >> 3;
  const int cs = (lane & 7) ^ rl;  // pre-swizzled source chunk

  auto stage = [&](int kv, int b) {
#pragma unroll
    for (int i = 0; i < 2; ++i) {
      const int r = (i * 4 + wave) * 8 + rl;
      gload_lds16(Kg + (size_t)(kv * 64 + r) * LDQK + h * D_HEAD + cs * 8,
                  &Ks[b][(i * 4 + wave) * 512]);
      gload_lds16(Vt + (size_t)(h * D_HEAD + r) * L_SEQ + kv * 64 + cs * 8,
                  &Vs[b][(i * 4 + wave) * 512]);
    }
  };

  // Q B-fragments first (VMEM-counted; drained by the first vmcnt(4))
  bf16x8 qf[4];
  {
    const __bf16* qp = Q + (size_t)q * LDQK + h * D_HEAD + hl * 8;
#pragma unroll
    for (int s = 0; s < 4; ++s) qf[s] = *(const bf16x8*)(qp + s * 16);
  }

  stage(0, 0);

  f32x16 acc0 = {}, acc1 = {};  // O^T[d][q], d-tiles 0/1
  float m = -1e30f, lsum = 0.f;

  int bc = 0;  // compute buffer = kv % 3
  for (int kv = 0; kv < nt; ++kv) {
    if (kv + 1 < nt) {
      int bs = bc + 1; if (bs == 3) bs = 0;
      stage(kv + 1, bs);
      asm volatile("s_waitcnt vmcnt(4)" ::: "memory");
    } else {
      asm volatile("s_waitcnt vmcnt(0)" ::: "memory");
    }
    __builtin_amdgcn_sched_barrier(0);
    __builtin_amdgcn_s_barrier();
    __builtin_amdgcn_sched_barrier(0);

    if (kv <= kvmax_w) {
      char* const KsB = (char*)&Ks[bc][0];
      char* const VsB = (char*)&Vs[bc][0];

      // S^T = K . Q^T : lane holds q=l31, key rows kr(reg)+{0,32}
      f32x16 st0 = {}, st1 = {};
      __builtin_amdgcn_s_setprio(1);
#pragma unroll
      for (int s = 0; s < 4; ++s) {
        const int ch = s * 2 + hl;
        bf16x8 a0 = *(const bf16x8*)(KsB + l31 * 128 + ((ch ^ (l31 & 7)) << 4));
        bf16x8 a1 = *(const bf16x8*)(KsB + (32 + l31) * 128 + ((ch ^ (l31 & 7)) << 4));
        st0 = __builtin_amdgcn_mfma_f32_32x32x16_bf16(a0, qf[s], st0, 0, 0, 0);
        st1 = __builtin_amdgcn_mfma_f32_32x32x16_bf16(a1, qf[s], st1, 0, 0, 0);
      }
      __builtin_amdgcn_s_setprio(0);

      // causal mask: only the (always-partial) last tile of this warp
      if (kv == kvmax_w) {
#pragma unroll
        for (int r = 0; r < 16; ++r) {
          const int kr = (r & 3) + 8 * (r >> 2) + 4 * hl;
          const int k0 = kv * 64 + kr;
          st0[r] = (k0 <= q) ? st0[r] : -1e30f;
          st1[r] = (k0 + 32 <= q) ? st1[r] : -1e30f;
        }
      }

      // row max: in-lane tree + one cross-half swap
      float t[16];
#pragma unroll
      for (int r = 0; r < 16; ++r) t[r] = fmaxf(st0[r], st1[r]);
#pragma unroll
      for (int w = 8; w > 0; w >>= 1)
#pragma unroll
        for (int r = 0; r < w; ++r) t[r] = fmaxf(t[r], t[r + w]);
      float mx = fmaxf(t[0], __shfl_xor(t[0], 32, 64));
      const float mnew = fmaxf(m, mx);
      const float corr = exp2f(m - mnew);
      m = mnew;

      // exp2 + row sum
#pragma unroll
      for (int r = 0; r < 16; ++r) {
        st0[r] = exp2f(st0[r] - m);
        st1[r] = exp2f(st1[r] - m);
      }
      float sm[16];
#pragma unroll
      for (int r = 0; r < 16; ++r) sm[r] = st0[r] + st1[r];
#pragma unroll
      for (int w = 8; w > 0; w >>= 1)
#pragma unroll
        for (int r = 0; r < w; ++r) sm[r] = sm[r] + sm[r + w];
      float sl = sm[0] + __shfl_xor(sm[0], 32, 64);
      lsum = lsum * corr + sl;
      acc0 *= corr;
      acc1 *= corr;

      // P -> bf16 pk words (pairs of consecutive keys)
      u32 w0[8], w1[8];
#pragma unroll
      for (int i = 0; i < 8; ++i) {
        asm("v_cvt_pk_bf16_f32 %0, %1, %2" : "=v"(w0[i]) : "v"(st0[2 * i]), "v"(st0[2 * i + 1]));
        asm("v_cvt_pk_bf16_f32 %0, %1, %2" : "=v"(w1[i]) : "v"(st1[2 * i]), "v"(st1[2 * i + 1]));
      }
      // cross-half exchange: one shfl serves both directions
      u32 e0a = (u32)__shfl_xor((int)(hl ? w0[0] : w0[2]), 32, 64);
      u32 e0b = (u32)__shfl_xor((int)(hl ? w0[1] : w0[3]), 32, 64);
      u32 e0c = (u32)__shfl_xor((int)(hl ? w0[4] : w0[6]), 32, 64);
      u32 e0d = (u32)__shfl_xor((int)(hl ? w0[5] : w0[7]), 32, 64);
      u32 e1a = (u32)__shfl_xor((int)(hl ? w1[0] : w1[2]), 32, 64);
      u32 e1b = (u32)__shfl_xor((int)(hl ? w1[1] : w1[3]), 32, 64);
      u32 e1c = (u32)__shfl_xor((int)(hl ? w1[4] : w1[6]), 32, 64);
      u32 e1d = (u32)__shfl_xor((int)(hl ? w1[5] : w1[7]), 32, 64);
      u32x4 f0 = hl ? (u32x4){e0a, e0b, w0[2], w0[3]} : (u32x4){w0[0], w0[1], e0a, e0b};
      u32x4 f1 = hl ? (u32x4){e0c, e0d, w0[6], w0[7]} : (u32x4){w0[4], w0[5], e0c, e0d};
      u32x4 f2 = hl ? (u32x4){e1a, e1b, w1[2], w1[3]} : (u32x4){w1[0], w1[1], e1a, e1b};
      u32x4 f3 = hl ? (u32x4){e1c, e1d, w1[6], w1[7]} : (u32x4){w1[4], w1[5], e1c, e1d};
      bf16x8 pb0 = __builtin_bit_cast(bf16x8, f0);
      bf16x8 pb1 = __builtin_bit_cast(bf16x8, f1);
      bf16x8 pb2 = __builtin_bit_cast(bf16x8, f2);
      bf16x8 pb3 = __builtin_bit_cast(bf16x8, f3);

      // O^T += V^T . P^T
      __builtin_amdgcn_s_setprio(1);
#pragma unroll
      for (int s = 0; s < 4; ++s) {
        const bf16x8 pb = (s == 0) ? pb0 : (s == 1) ? pb1 : (s == 2) ? pb2 : pb3;
        const int ch = s * 2 + hl;
        bf16x8 va0 = *(const bf16x8*)(VsB + l31 * 128 + ((ch ^ (l31 & 7)) << 4));
        bf16x8 va1 = *(const bf16x8*)(VsB + (32 + l31) * 128 + ((ch ^ (l31 & 7)) << 4));
        acc0 = __builtin_amdgcn_mfma_f32_32x32x16_bf16(va0, pb, acc0, 0, 0, 0);
        acc1 = __builtin_amdgcn_mfma_f32_32x32x16_bf16(va1, pb, acc1, 0, 0, 0);
      }
      __builtin_amdgcn_s_setprio(0);
    }

    bc = bc + 1; if (bc == 3) bc = 0;
  }

  // epilogue: normalize, transpose O^T->O via per-warp swizzled LDS, store
  const float rinv = 1.0f / lsum;
  char* const Po = (char*)&PoS[wave][0];
#pragma unroll
  for (int dt = 0; dt < 2; ++dt) {
#pragma unroll
    for (int i = 0; i < 8; ++i) {
      const int r = 2 * i;
      const int d = dt * 32 + (r & 3) + 8 * (r >> 2) + 4 * hl;
      float lo = (dt ? acc1[r] : acc0[r]) * rinv;
      float hi = (dt ? acc1[r + 1] : acc0[r + 1]) * rinv;
      u32 wv;
      asm("v_cvt_pk_bf16_f32 %0, %1, %2" : "=v"(wv) : "v"(lo), "v"(hi));
      *(u32*)(Po + l31 * 128 + (((d >> 3) ^ (l31 & 7)) << 4) + (d & 7) * 2) = wv;
    }
  }
  asm volatile("s_waitcnt lgkmcnt(0)" ::: "memory");
  __builtin_amdgcn_sched_barrier(0);
#pragma unroll
  for (int j = 0; j < 4; ++j) {
    const int qr = lane >> 1;
    const int c = (lane & 1) * 4 + j;
    bf16x8 ov = *(const bf16x8*)(Po + qr * 128 + ((c ^ (qr & 7)) << 4));
    *(bf16x8*)(O + (size_t)(qbase + qr) * C_DIM + h * D_HEAD + c * 8) = ov;
  }
}

extern "C" void kernel_launch(void* const* d_in, const int* in_sizes, int n_in,
                              void* d_out, int out_size, void* d_ws, size_t ws_size,
                              hipStream_t stream) {
  const float* x = (const float*)d_in[0];
  const float* Wq = (const float*)d_in[1];
  const float* Wk = (const float*)d_in[2];
  const float* Wv = (const float*)d_in[3];
  const float* Wo = (const float*)d_in[4];
  float* out = (float*)d_out;

  char* ws = (char*)d_ws;
  __bf16* xb    = (__bf16*)(ws);                 // [0,8M) x bf16; reused as Ab
  __bf16* WqkvT = (__bf16*)(ws + (8u << 20));    // [8M,16M) WqT,WkT,WvT,WoT
  __bf16* QKb   = (__bf16*)(ws + (16u << 20));   // [16M,32M) 4096x2048
  __bf16* Vtb   = (__bf16*)(ws + (32u << 20));   // [32M,40M) 1024x4096
  __bf16* WvT   = WqkvT + (size_t)2 * 1048576;
  __bf16* WoT   = WqkvT + (size_t)3 * 1048576;
  __bf16* Ab    = xb;

  prep<<<8192, 256, 0, stream>>>(x, Wq, Wk, Wv, Wo, xb, WqkvT);

  gemm_qkv<<<768, 256, 0, stream>>>(xb, WqkvT, WvT, QKb, Vtb);

  attn_fwd<<<512, 256, 0, stream>>>(QKb, QKb + 1024, Vtb, Ab);

  gemm_bt<false><<<dim3(32, 8), 256, 0, stream>>>(
      Ab, WoT, out, L_SEQ, C_DIM, C_DIM, 1.0f, 0);
}